// Round 4
// baseline (316.827 us; speedup 1.0000x reference)
//
#include <hip/hip_runtime.h>
#include <hip/hip_bf16.h>

typedef __attribute__((ext_vector_type(8))) short short8;
typedef __attribute__((ext_vector_type(4))) float floatx4;

constexpr int Sdim = 2048;
constexpr int Hdim = 1024;
constexpr int NH   = 16;
constexpr int HD   = 64;

__device__ __forceinline__ unsigned short f2bf(float f) {
    unsigned int x = __builtin_bit_cast(unsigned int, f);
    unsigned int r = (x + 0x7fffu + ((x >> 16) & 1u)) >> 16;
    return (unsigned short)r;
}

// load 8 consecutive fp32, convert to 8 bf16 (RNE)
__device__ __forceinline__ short8 cvt8(const float* __restrict__ p) {
    floatx4 a = *(const floatx4*)p;
    floatx4 b = *(const floatx4*)(p + 4);
    short8 r;
    r[0] = (short)f2bf(a[0]); r[1] = (short)f2bf(a[1]);
    r[2] = (short)f2bf(a[2]); r[3] = (short)f2bf(a[3]);
    r[4] = (short)f2bf(b[0]); r[5] = (short)f2bf(b[1]);
    r[6] = (short)f2bf(b[2]); r[7] = (short)f2bf(b[3]);
    return r;
}

// ---------------------------------------------------------------------------
// Kernel 1: K/V projection only (Q is fused into the attention kernel).
// out = x @ W^T (+bias), fp32 in, bf16 out into [b, h, s, d] layout.
// grid = (N/64, M/64, 2); block = 256 (4 waves).  Workspace: 16 MiB total.
// ---------------------------------------------------------------------------
__global__ __launch_bounds__(256) void kv_proj_kernel(
    const float* __restrict__ Wk,
    const float* __restrict__ Wv,
    const float* __restrict__ bv,
    const float* __restrict__ X,
    unsigned short* __restrict__ ko,
    unsigned short* __restrict__ vo)
{
    const int which = blockIdx.z;              // 0 = K (no bias), 1 = V (+bv)
    const float* W    = (which == 0) ? Wk : Wv;
    const float* bias = (which == 0) ? nullptr : bv;
    unsigned short* outp = (which == 0) ? ko : vo;

    // +8 pad -> 80B row stride -> 2-way LDS bank aliasing (free per m136)
    __shared__ unsigned short As[64 * 40];
    __shared__ unsigned short Bs[64 * 40];

    const int tid  = threadIdx.x;
    const int wave = tid >> 6;
    const int lane = tid & 63;
    const int quad = lane >> 4;
    const int l16  = lane & 15;

    const int m0 = blockIdx.y * 64;
    const int n0 = blockIdx.x * 64;

    floatx4 acc[4];
#pragma unroll
    for (int i = 0; i < 4; ++i) acc[i] = (floatx4){0.f, 0.f, 0.f, 0.f};

    const int srow = tid >> 2;        // 0..63
    const int skof = (tid & 3) * 8;   // 0,8,16,24

    for (int k0 = 0; k0 < Hdim; k0 += 32) {
        *(short8*)(As + srow * 40 + skof) =
            cvt8(X + (size_t)(m0 + srow) * Hdim + k0 + skof);
        *(short8*)(Bs + srow * 40 + skof) =
            cvt8(W + (size_t)(n0 + srow) * Hdim + k0 + skof);
        __syncthreads();

        // A frag: m = lane&15, k = quad*8+j
        short8 af = *(const short8*)(As + (wave * 16 + l16) * 40 + quad * 8);
#pragma unroll
        for (int nt = 0; nt < 4; ++nt) {
            // B frag: n = lane&15, k = quad*8+j
            short8 bf = *(const short8*)(Bs + (nt * 16 + l16) * 40 + quad * 8);
            acc[nt] = __builtin_amdgcn_mfma_f32_16x16x32_bf16(af, bf, acc[nt], 0, 0, 0);
        }
        __syncthreads();
    }

    // Epilogue: C/D layout col = lane&15, row = quad*4 + reg
#pragma unroll
    for (int nt = 0; nt < 4; ++nt) {
        const int n = n0 + nt * 16 + l16;
        const float bval = bias ? bias[n] : 0.0f;
        const int h = n >> 6, dd = n & 63;
#pragma unroll
        for (int reg = 0; reg < 4; ++reg) {
            const int m = m0 + wave * 16 + quad * 4 + reg;
            const int b = m >> 11, s = m & 2047;
            outp[((size_t)(b * NH + h) * Sdim + s) * HD + dd] = f2bf(acc[nt][reg] + bval);
        }
    }
}

// ---------------------------------------------------------------------------
// Kernel 2: fused Q-projection + flash attention.
// grid = (S/64 q-tiles, B*NH); block = 256 (4 waves; 16 q-rows per wave).
// Prologue computes q = (X @ Wq^T + bq) * 0.125 for this block's 64x64 tile
// (64 q-rows x one head) straight into A-operand fragments.  fp32 output.
// ---------------------------------------------------------------------------
__global__ __launch_bounds__(256) void attn_kernel(
    const float* __restrict__ X,
    const float* __restrict__ Wq,
    const float* __restrict__ bq,
    const unsigned short* __restrict__ kw,
    const unsigned short* __restrict__ vw,
    const float* __restrict__ mask,
    float* __restrict__ out)
{
    // 72-elem rows: 144B stride -> 2-way bank aliasing (free)
    __shared__ unsigned short Kt[64 * 72];      // [key][d]   (also As: 64x40)
    __shared__ unsigned short Vt[64 * 72];      // [d][key]   (also Bs: 64x40)
    __shared__ unsigned short Pt[4][16 * 72];   // per-wave C->A round-trip

    const int tid  = threadIdx.x;
    const int wave = tid >> 6;
    const int lane = tid & 63;
    const int quad = lane >> 4;
    const int l16  = lane & 15;

    const int bh = blockIdx.y;
    const int b  = bh >> 4;
    const int h  = bh & 15;
    const int q0 = blockIdx.x * 64;

    const unsigned short* K = kw + (size_t)bh * Sdim * HD;
    const unsigned short* V = vw + (size_t)bh * Sdim * HD;
    const float* mg = mask + (size_t)b * Sdim;

    const int srow = tid >> 2;        // 0..63
    const int skof = (tid & 3) * 8;   // 0,8,16,24

    // ================= Q-projection prologue =================
    floatx4 qacc[4];
#pragma unroll
    for (int i = 0; i < 4; ++i) qacc[i] = (floatx4){0.f, 0.f, 0.f, 0.f};

    {
        unsigned short* As = Kt;   // 64 x 40
        unsigned short* Bs = Vt;   // 64 x 40
        const float* Xrow = X + (size_t)(b * Sdim + q0) * Hdim;
        const float* Wrow = Wq + (size_t)(h * HD) * Hdim;
        for (int k0 = 0; k0 < Hdim; k0 += 32) {
            *(short8*)(As + srow * 40 + skof) = cvt8(Xrow + (size_t)srow * Hdim + k0 + skof);
            *(short8*)(Bs + srow * 40 + skof) = cvt8(Wrow + (size_t)srow * Hdim + k0 + skof);
            __syncthreads();
            short8 af = *(const short8*)(As + (wave * 16 + l16) * 40 + quad * 8);
#pragma unroll
            for (int nt = 0; nt < 4; ++nt) {
                short8 bf = *(const short8*)(Bs + (nt * 16 + l16) * 40 + quad * 8);
                qacc[nt] = __builtin_amdgcn_mfma_f32_16x16x32_bf16(af, bf, qacc[nt], 0, 0, 0);
            }
            __syncthreads();
        }
    }

    // bias + scale, C/D layout -> LDS -> A-operand fragments
    short8 qf[2];
    {
        unsigned short* Pw = Pt[wave];
#pragma unroll
        for (int nt = 0; nt < 4; ++nt) {
            const float bval = bq[h * HD + nt * 16 + l16];
#pragma unroll
            for (int reg = 0; reg < 4; ++reg)
                Pw[(quad * 4 + reg) * 72 + nt * 16 + l16] =
                    f2bf((qacc[nt][reg] + bval) * 0.125f);
        }
        __syncthreads();
        qf[0] = *(const short8*)(Pw + l16 * 72 + quad * 8);
        qf[1] = *(const short8*)(Pw + l16 * 72 + 32 + quad * 8);
        __syncthreads();
    }

    // ================= flash attention main loop =================
    float mcur[4], lcur[4];
    floatx4 oacc[4];
#pragma unroll
    for (int r = 0; r < 4; ++r) { mcur[r] = -1e30f; lcur[r] = 0.f; }
#pragma unroll
    for (int t = 0; t < 4; ++t) oacc[t] = (floatx4){0.f, 0.f, 0.f, 0.f};

    for (int kt = 0; kt < Sdim; kt += 64) {
        // ---- stage K [key][d] and V transposed [d][key] ----
#pragma unroll
        for (int i = 0; i < 2; ++i) {
            const int c   = tid + 256 * i;   // 0..511
            const int row = c >> 3;          // key 0..63
            const int off = (c & 7) * 8;     // d offset
            *(short8*)(Kt + row * 72 + off) =
                *(const short8*)(K + (size_t)(kt + row) * HD + off);
            short8 vv = *(const short8*)(V + (size_t)(kt + row) * HD + off);
#pragma unroll
            for (int j = 0; j < 8; ++j)
                Vt[(off + j) * 72 + row] = (unsigned short)vv[j];
        }
        __syncthreads();

        // ---- scores: S = Q K^T  (16 q-rows x 64 keys per wave) ----
        float sc[4][4];
#pragma unroll
        for (int nt = 0; nt < 4; ++nt) {
            const unsigned short* kp = Kt + (nt * 16 + l16) * 72 + quad * 8;
            short8 kf0 = *(const short8*)(kp);
            short8 kf1 = *(const short8*)(kp + 32);
            floatx4 s = (floatx4){0.f, 0.f, 0.f, 0.f};
            s = __builtin_amdgcn_mfma_f32_16x16x32_bf16(qf[0], kf0, s, 0, 0, 0);
            s = __builtin_amdgcn_mfma_f32_16x16x32_bf16(qf[1], kf1, s, 0, 0, 0);
            const float madd = mg[kt + nt * 16 + l16];
#pragma unroll
            for (int reg = 0; reg < 4; ++reg) sc[nt][reg] = s[reg] + madd;
        }

        // ---- online softmax (rows = quad*4+reg; reduce across 16 lanes) ----
        float alpha[4];
#pragma unroll
        for (int reg = 0; reg < 4; ++reg) {
            float t = fmaxf(fmaxf(sc[0][reg], sc[1][reg]), fmaxf(sc[2][reg], sc[3][reg]));
            t = fmaxf(t, __shfl_xor(t, 1));
            t = fmaxf(t, __shfl_xor(t, 2));
            t = fmaxf(t, __shfl_xor(t, 4));
            t = fmaxf(t, __shfl_xor(t, 8));
            const float mnew = fmaxf(mcur[reg], t);
            alpha[reg] = __expf(mcur[reg] - mnew);
            mcur[reg] = mnew;
        }
#pragma unroll
        for (int reg = 0; reg < 4; ++reg) {
            float ps = 0.f;
#pragma unroll
            for (int nt = 0; nt < 4; ++nt) {
                const float p = __expf(sc[nt][reg] - mcur[reg]);
                sc[nt][reg] = p;
                ps += p;
            }
            ps += __shfl_xor(ps, 1);
            ps += __shfl_xor(ps, 2);
            ps += __shfl_xor(ps, 4);
            ps += __shfl_xor(ps, 8);
            lcur[reg] = lcur[reg] * alpha[reg] + ps;
        }
#pragma unroll
        for (int t = 0; t < 4; ++t)
#pragma unroll
            for (int reg = 0; reg < 4; ++reg) oacc[t][reg] *= alpha[reg];

        // ---- P: C/D layout -> LDS -> A layout ----
        unsigned short* Pw = Pt[wave];
#pragma unroll
        for (int nt = 0; nt < 4; ++nt)
#pragma unroll
            for (int reg = 0; reg < 4; ++reg)
                Pw[(quad * 4 + reg) * 72 + nt * 16 + l16] = f2bf(sc[nt][reg]);
        __syncthreads();

        // ---- O += P V ----
#pragma unroll
        for (int c = 0; c < 2; ++c) {
            short8 pf = *(const short8*)(Pw + l16 * 72 + c * 32 + quad * 8);
#pragma unroll
            for (int dt = 0; dt < 4; ++dt) {
                short8 vf = *(const short8*)(Vt + (dt * 16 + l16) * 72 + c * 32 + quad * 8);
                oacc[dt] = __builtin_amdgcn_mfma_f32_16x16x32_bf16(pf, vf, oacc[dt], 0, 0, 0);
            }
        }
        __syncthreads();   // protect Kt/Vt before next stage
    }

    // ---- epilogue: out[b, s, h*64+dd] = O / l  (fp32 output) ----
#pragma unroll
    for (int dt = 0; dt < 4; ++dt) {
        const int dd = dt * 16 + l16;
#pragma unroll
        for (int reg = 0; reg < 4; ++reg) {
            const int s = q0 + wave * 16 + quad * 4 + reg;
            const float val = oacc[dt][reg] / lcur[reg];
            out[((size_t)(b * Sdim + s)) * Hdim + h * HD + dd] = val;
        }
    }
}

extern "C" void kernel_launch(void* const* d_in, const int* in_sizes, int n_in,
                              void* d_out, int out_size, void* d_ws, size_t ws_size,
                              hipStream_t stream) {
    const float* X    = (const float*)d_in[0];
    const float* mask = (const float*)d_in[1];
    const float* Wq   = (const float*)d_in[2];
    const float* bq   = (const float*)d_in[3];
    const float* Wk   = (const float*)d_in[4];
    const float* Wv   = (const float*)d_in[5];
    const float* bv   = (const float*)d_in[6];
    float* out = (float*)d_out;

    // workspace: k,v bf16 [B,NH,S,HD] -> 2 x 8 MiB = 16 MiB total
    unsigned short* kws = (unsigned short*)d_ws;
    unsigned short* vws = kws + (size_t)4096 * 1024;

    kv_proj_kernel<<<dim3(16, 64, 2), 256, 0, stream>>>(
        Wk, Wv, bv, X, kws, vws);
    attn_kernel<<<dim3(32, 32), 256, 0, stream>>>(
        X, Wq, bq, kws, vws, mask, out);
}

// Round 6
// 282.534 us; speedup vs baseline: 1.1214x; 1.1214x over previous
//
#include <hip/hip_runtime.h>
#include <hip/hip_bf16.h>

typedef __attribute__((ext_vector_type(4))) short bfx4;
typedef __attribute__((ext_vector_type(8))) short short8;
typedef __attribute__((ext_vector_type(4))) float floatx4;

constexpr int Sdim = 2048;
constexpr int Hdim = 1024;
constexpr int NH   = 16;
constexpr int HD   = 64;

__device__ __forceinline__ unsigned short f2bf(float f) {
    unsigned int x = __builtin_bit_cast(unsigned int, f);
    unsigned int r = (x + 0x7fffu + ((x >> 16) & 1u)) >> 16;
    return (unsigned short)r;
}

// load 8 consecutive fp32, convert to 8 bf16 (RNE)
__device__ __forceinline__ short8 cvt8(const float* __restrict__ p) {
    floatx4 a = *(const floatx4*)p;
    floatx4 b = *(const floatx4*)(p + 4);
    short8 r;
    r[0] = (short)f2bf(a[0]); r[1] = (short)f2bf(a[1]);
    r[2] = (short)f2bf(a[2]); r[3] = (short)f2bf(a[3]);
    r[4] = (short)f2bf(b[0]); r[5] = (short)f2bf(b[1]);
    r[6] = (short)f2bf(b[2]); r[7] = (short)f2bf(b[3]);
    return r;
}

// ---------------------------------------------------------------------------
// Kernel 1: K/V projection (Q fused into attention kernel).
// K -> [b,h,s,d] bf16;  V -> TRANSPOSED [b,h,d,s] bf16 (so attention stages
// its [d][key] LDS tile with vector copies, no scalar-write transpose).
// grid = (N/64, M/64, 2); block = 256 (4 waves).  BK = 64.
// ---------------------------------------------------------------------------
__global__ __launch_bounds__(256) void kv_proj_kernel(
    const float* __restrict__ Wk,
    const float* __restrict__ Wv,
    const float* __restrict__ bv,
    const float* __restrict__ X,
    unsigned short* __restrict__ ko,
    unsigned short* __restrict__ vo)
{
    const int which = blockIdx.z;              // 0 = K (no bias), 1 = V (+bv)
    const float* W = (which == 0) ? Wk : Wv;

    // 72-elem rows: 144B stride, 2-way bank aliasing = free (m136)
    __shared__ unsigned short As[64 * 72];
    __shared__ unsigned short Bs[64 * 72];

    const int tid  = threadIdx.x;
    const int wave = tid >> 6;
    const int lane = tid & 63;
    const int quad = lane >> 4;
    const int l16  = lane & 15;

    const int m0 = blockIdx.y * 64;   // rows (b,s)
    const int n0 = blockIdx.x * 64;   // cols (h,d)

    floatx4 acc[4];
#pragma unroll
    for (int i = 0; i < 4; ++i) acc[i] = (floatx4){0.f, 0.f, 0.f, 0.f};

    const float* Xrow = X + (size_t)m0 * Hdim;
    const float* Wrow = W + (size_t)n0 * Hdim;

    for (int k0 = 0; k0 < Hdim; k0 += 64) {
#pragma unroll
        for (int i = 0; i < 2; ++i) {
            const int t    = tid + 256 * i;   // 0..511
            const int row  = t >> 3;          // 0..63
            const int koff = (t & 7) * 8;     // 0..56
            *(short8*)(As + row * 72 + koff) = cvt8(Xrow + (size_t)row * Hdim + k0 + koff);
            *(short8*)(Bs + row * 72 + koff) = cvt8(Wrow + (size_t)row * Hdim + k0 + koff);
        }
        __syncthreads();
#pragma unroll
        for (int c = 0; c < 2; ++c) {
            short8 af = *(const short8*)(As + (wave * 16 + l16) * 72 + c * 32 + quad * 8);
#pragma unroll
            for (int nt = 0; nt < 4; ++nt) {
                short8 bf = *(const short8*)(Bs + (nt * 16 + l16) * 72 + c * 32 + quad * 8);
                acc[nt] = __builtin_amdgcn_mfma_f32_16x16x32_bf16(af, bf, acc[nt], 0, 0, 0);
            }
        }
        __syncthreads();
    }

    const int b  = m0 >> 11;        // batch (block-uniform)
    const int s0 = m0 & 2047;       // seq base
    const int h  = n0 >> 6;         // head  (block-uniform; n0 multiple of 64)

    if (which == 0) {
        // ---- K epilogue: [b,h,s,d]; C/D layout col=lane&15, row=quad*4+reg
#pragma unroll
        for (int nt = 0; nt < 4; ++nt) {
            const int dd = nt * 16 + l16;
#pragma unroll
            for (int reg = 0; reg < 4; ++reg) {
                const int s = s0 + wave * 16 + quad * 4 + reg;
                ko[((size_t)(b * NH + h) * Sdim + s) * HD + dd] = f2bf(acc[nt][reg]);
            }
        }
    } else {
        // ---- V epilogue: transpose through LDS, store [b,h,d,s] coalesced
        unsigned short* Vl = As;   // 64 x 72, overlays As (main loop done)
#pragma unroll
        for (int nt = 0; nt < 4; ++nt) {
            const float bval = bv[n0 + nt * 16 + l16];
            bfx4 p;
#pragma unroll
            for (int reg = 0; reg < 4; ++reg) p[reg] = (short)f2bf(acc[nt][reg] + bval);
            *(bfx4*)(Vl + (nt * 16 + l16) * 72 + wave * 16 + quad * 4) = p;
        }
        __syncthreads();
#pragma unroll
        for (int i = 0; i < 2; ++i) {
            const int t   = tid + 256 * i;    // 0..511
            const int dd  = t >> 3;           // 0..63
            const int off = (t & 7) * 8;      // 0..56 (s offset)
            *(short8*)(vo + ((size_t)(b * NH + h) * HD + dd) * Sdim + s0 + off) =
                *(const short8*)(Vl + dd * 72 + off);
        }
    }
}

// ---------------------------------------------------------------------------
// Kernel 2: fused Q-projection + flash attention.
// grid = (S/64 q-tiles, B*NH); block = 256 (4 waves; 16 q-rows per wave).
// V arrives pre-transposed [b,h,d,s] -> Vt staged with vector copies.
// q pre-scaled by 1/8.  fp32 output.
// ---------------------------------------------------------------------------
__global__ __launch_bounds__(256) void attn_kernel(
    const float* __restrict__ X,
    const float* __restrict__ Wq,
    const float* __restrict__ bq,
    const unsigned short* __restrict__ kw,
    const unsigned short* __restrict__ vw,
    const float* __restrict__ mask,
    float* __restrict__ out)
{
    __shared__ unsigned short Kt[64 * 72];      // [key][d]   (prologue: As)
    __shared__ unsigned short Vt[64 * 72];      // [d][key]   (prologue: Bs)
    __shared__ unsigned short Pt[4][16 * 72];   // per-wave C->A round-trip

    const int tid  = threadIdx.x;
    const int wave = tid >> 6;
    const int lane = tid & 63;
    const int quad = lane >> 4;
    const int l16  = lane & 15;

    const int bh = blockIdx.y;
    const int b  = bh >> 4;
    const int h  = bh & 15;
    const int q0 = blockIdx.x * 64;

    const unsigned short* K  = kw + (size_t)bh * Sdim * HD;   // [key][d]
    const unsigned short* Vg = vw + (size_t)bh * HD * Sdim;   // [d][key]
    const float* mg = mask + (size_t)b * Sdim;

    // ================= Q-projection prologue (BK=64) =================
    floatx4 qacc[4];
#pragma unroll
    for (int i = 0; i < 4; ++i) qacc[i] = (floatx4){0.f, 0.f, 0.f, 0.f};
    {
        unsigned short* As = Kt;
        unsigned short* Bs = Vt;
        const float* Xrow = X + (size_t)(b * Sdim + q0) * Hdim;
        const float* Wrow = Wq + (size_t)(h * HD) * Hdim;
        for (int k0 = 0; k0 < Hdim; k0 += 64) {
#pragma unroll
            for (int i = 0; i < 2; ++i) {
                const int t    = tid + 256 * i;
                const int row  = t >> 3;
                const int koff = (t & 7) * 8;
                *(short8*)(As + row * 72 + koff) = cvt8(Xrow + (size_t)row * Hdim + k0 + koff);
                *(short8*)(Bs + row * 72 + koff) = cvt8(Wrow + (size_t)row * Hdim + k0 + koff);
            }
            __syncthreads();
#pragma unroll
            for (int c = 0; c < 2; ++c) {
                short8 af = *(const short8*)(As + (wave * 16 + l16) * 72 + c * 32 + quad * 8);
#pragma unroll
                for (int nt = 0; nt < 4; ++nt) {
                    short8 bf = *(const short8*)(Bs + (nt * 16 + l16) * 72 + c * 32 + quad * 8);
                    qacc[nt] = __builtin_amdgcn_mfma_f32_16x16x32_bf16(af, bf, qacc[nt], 0, 0, 0);
                }
            }
            __syncthreads();
        }
    }

    // bias + scale, C/D layout -> LDS -> A-operand fragments
    short8 qf[2];
    {
        unsigned short* Pw = Pt[wave];
#pragma unroll
        for (int nt = 0; nt < 4; ++nt) {
            const float bval = bq[h * HD + nt * 16 + l16];
#pragma unroll
            for (int reg = 0; reg < 4; ++reg)
                Pw[(quad * 4 + reg) * 72 + nt * 16 + l16] =
                    f2bf((qacc[nt][reg] + bval) * 0.125f);
        }
        __syncthreads();
        qf[0] = *(const short8*)(Pw + l16 * 72 + quad * 8);
        qf[1] = *(const short8*)(Pw + l16 * 72 + 32 + quad * 8);
        __syncthreads();
    }

    // ================= flash attention main loop =================
    float mcur[4], lcur[4];
    floatx4 oacc[4];
#pragma unroll
    for (int r = 0; r < 4; ++r) { mcur[r] = -1e30f; lcur[r] = 0.f; }
#pragma unroll
    for (int t = 0; t < 4; ++t) oacc[t] = (floatx4){0.f, 0.f, 0.f, 0.f};

    for (int kt = 0; kt < Sdim; kt += 64) {
        // ---- stage K [key][d] and V [d][key] — all vector copies ----
#pragma unroll
        for (int i = 0; i < 2; ++i) {
            const int t   = tid + 256 * i;   // 0..511
            const int row = t >> 3;          // K: key 0..63 / V: d 0..63
            const int off = (t & 7) * 8;     // K: d offset  / V: key offset
            *(short8*)(Kt + row * 72 + off) =
                *(const short8*)(K + (size_t)(kt + row) * HD + off);
            *(short8*)(Vt + row * 72 + off) =
                *(const short8*)(Vg + (size_t)row * Sdim + kt + off);
        }
        __syncthreads();

        // ---- scores: S = Q K^T  (16 q-rows x 64 keys per wave) ----
        float sc[4][4];
#pragma unroll
        for (int nt = 0; nt < 4; ++nt) {
            const unsigned short* kp = Kt + (nt * 16 + l16) * 72 + quad * 8;
            short8 kf0 = *(const short8*)(kp);
            short8 kf1 = *(const short8*)(kp + 32);
            floatx4 s = (floatx4){0.f, 0.f, 0.f, 0.f};
            s = __builtin_amdgcn_mfma_f32_16x16x32_bf16(qf[0], kf0, s, 0, 0, 0);
            s = __builtin_amdgcn_mfma_f32_16x16x32_bf16(qf[1], kf1, s, 0, 0, 0);
            const float madd = mg[kt + nt * 16 + l16];
#pragma unroll
            for (int reg = 0; reg < 4; ++reg) sc[nt][reg] = s[reg] + madd;
        }

        // ---- online softmax (rows = quad*4+reg; reduce across 16 lanes) ----
        float alpha[4];
#pragma unroll
        for (int reg = 0; reg < 4; ++reg) {
            float t = fmaxf(fmaxf(sc[0][reg], sc[1][reg]), fmaxf(sc[2][reg], sc[3][reg]));
            t = fmaxf(t, __shfl_xor(t, 1));
            t = fmaxf(t, __shfl_xor(t, 2));
            t = fmaxf(t, __shfl_xor(t, 4));
            t = fmaxf(t, __shfl_xor(t, 8));
            const float mnew = fmaxf(mcur[reg], t);
            alpha[reg] = __expf(mcur[reg] - mnew);
            mcur[reg] = mnew;
        }
#pragma unroll
        for (int reg = 0; reg < 4; ++reg) {
            float ps = 0.f;
#pragma unroll
            for (int nt = 0; nt < 4; ++nt) {
                const float p = __expf(sc[nt][reg] - mcur[reg]);
                sc[nt][reg] = p;
                ps += p;
            }
            ps += __shfl_xor(ps, 1);
            ps += __shfl_xor(ps, 2);
            ps += __shfl_xor(ps, 4);
            ps += __shfl_xor(ps, 8);
            lcur[reg] = lcur[reg] * alpha[reg] + ps;
        }
#pragma unroll
        for (int t = 0; t < 4; ++t)
#pragma unroll
            for (int reg = 0; reg < 4; ++reg) oacc[t][reg] *= alpha[reg];

        // ---- P: C/D layout -> LDS -> A layout ----
        unsigned short* Pw = Pt[wave];
#pragma unroll
        for (int nt = 0; nt < 4; ++nt)
#pragma unroll
            for (int reg = 0; reg < 4; ++reg)
                Pw[(quad * 4 + reg) * 72 + nt * 16 + l16] = f2bf(sc[nt][reg]);
        __syncthreads();

        // ---- O += P V ----
#pragma unroll
        for (int c = 0; c < 2; ++c) {
            short8 pf = *(const short8*)(Pw + l16 * 72 + c * 32 + quad * 8);
#pragma unroll
            for (int dt = 0; dt < 4; ++dt) {
                short8 vf = *(const short8*)(Vt + (dt * 16 + l16) * 72 + c * 32 + quad * 8);
                oacc[dt] = __builtin_amdgcn_mfma_f32_16x16x32_bf16(pf, vf, oacc[dt], 0, 0, 0);
            }
        }
        __syncthreads();   // protect Kt/Vt before next stage
    }

    // ---- epilogue: out[b, s, h*64+dd] = O / l  (fp32 output) ----
#pragma unroll
    for (int dt = 0; dt < 4; ++dt) {
        const int dd = dt * 16 + l16;
#pragma unroll
        for (int reg = 0; reg < 4; ++reg) {
            const int s = q0 + wave * 16 + quad * 4 + reg;
            const float val = oacc[dt][reg] / lcur[reg];
            out[((size_t)(b * Sdim + s)) * Hdim + h * HD + dd] = val;
        }
    }
}

extern "C" void kernel_launch(void* const* d_in, const int* in_sizes, int n_in,
                              void* d_out, int out_size, void* d_ws, size_t ws_size,
                              hipStream_t stream) {
    const float* X    = (const float*)d_in[0];
    const float* mask = (const float*)d_in[1];
    const float* Wq   = (const float*)d_in[2];
    const float* bq   = (const float*)d_in[3];
    const float* Wk   = (const float*)d_in[4];
    const float* Wv   = (const float*)d_in[5];
    const float* bv   = (const float*)d_in[6];
    float* out = (float*)d_out;

    // workspace: k [b,h,s,d] + v^T [b,h,d,s] bf16 -> 16 MiB total
    unsigned short* kws = (unsigned short*)d_ws;
    unsigned short* vws = kws + (size_t)4096 * 1024;

    kv_proj_kernel<<<dim3(16, 64, 2), 256, 0, stream>>>(
        Wk, Wv, bv, X, kws, vws);
    attn_kernel<<<dim3(32, 32), 256, 0, stream>>>(
        X, Wq, bq, kws, vws, mask, out);
}